// Round 14
// baseline (1513.746 us; speedup 1.0000x reference)
//
#include <hip/hip_runtime.h>
#include <hip/hip_fp16.h>
#include <stdint.h>

#define SQRT_HALF_C 0.70710678118654752440f
#define GAMMA_C 1.3f
#define EPS_BN 1e-5f

typedef float f32x4 __attribute__((ext_vector_type(4)));
typedef __bf16 bf16x8 __attribute__((ext_vector_type(8)));

__device__ __forceinline__ unsigned short f2b(float f) {
    unsigned int u = __float_as_uint(f);
    unsigned int r = (u + 0x7FFFu + ((u >> 16) & 1u)) >> 16;
    return (unsigned short)r;
}
__device__ __forceinline__ float b2f(unsigned short b) {
    return __uint_as_float((unsigned int)b << 16);
}
__device__ __forceinline__ unsigned short f2h(float f) {
    return __half_as_ushort(__float2half(f));
}
__device__ __forceinline__ float h2f(unsigned short u) {
    return __half2float(__ushort_as_half(u));
}

__device__ __forceinline__ void gload_lds16(const void* g, void* l) {
    __builtin_amdgcn_global_load_lds((__attribute__((address_space(1))) void*)(g),
                                     (__attribute__((address_space(3))) void*)(l),
                                     16, 0, 0);
}

// ---------------------------------------------------------------------------
// Merged input/weight conversion kernel (one launch):
//   blocks [0, 8192)            : a (f32) -> a_bf (bf16), 4 elems/thread
//   blocks [8192, 8320)         : W_att transpose  (K=512,  N=1024)
//   blocks [8320, 10368)        : Wl[0..3] transpose (K=1024, N=2048) x4
//   blocks [10368, 10496)       : W_agg transpose  (K=512,  N=1024)
// Also zeroes the GEMM finale counter (block 0, thread 0).
// ---------------------------------------------------------------------------
__device__ __forceinline__ void transpose_tile(const float* __restrict__ W,
                                               unsigned short* __restrict__ WT,
                                               int K, int N, int bx, int by) {
    __shared__ float t[64][65];
    const int n0 = bx * 64;
    const int k0 = by * 64;
    const int tx = threadIdx.x & 63;
    const int ty = threadIdx.x >> 6;
    #pragma unroll
    for (int i = ty; i < 64; i += 4)
        t[i][tx] = W[(size_t)(k0 + i) * N + n0 + tx];
    __syncthreads();
    #pragma unroll
    for (int i = ty; i < 64; i += 4)
        WT[(size_t)(n0 + i) * K + k0 + tx] = f2b(t[tx][i]);
}

__global__ __launch_bounds__(256) void convert_all_kernel(const float* __restrict__ a,
                                                          unsigned short* __restrict__ a_bf,
                                                          const float* __restrict__ W_att,
                                                          unsigned short* __restrict__ wt_att,
                                                          const float* __restrict__ W0,
                                                          const float* __restrict__ W1,
                                                          const float* __restrict__ W2,
                                                          const float* __restrict__ W3,
                                                          unsigned short* __restrict__ wtl,
                                                          const float* __restrict__ W_agg,
                                                          unsigned short* __restrict__ wt_agg,
                                                          unsigned int* __restrict__ counter) {
    const int b = blockIdx.x;
    if (b == 0 && threadIdx.x == 0) *counter = 0u;
    if (b < 8192) {
        const int i = b * 256 + threadIdx.x;
        float4 v = *(const float4*)(a + (size_t)i * 4);
        ushort4 q;
        q.x = f2b(v.x); q.y = f2b(v.y); q.z = f2b(v.z); q.w = f2b(v.w);
        *(ushort4*)(a_bf + (size_t)i * 4) = q;
    } else if (b < 8320) {
        const int idx = b - 8192;           // 16 x 8
        transpose_tile(W_att, wt_att, 512, 1024, idx & 15, idx >> 4);
    } else if (b < 10368) {
        const int idx = b - 8320;           // 4 layers x (32 x 16)
        const int z = idx >> 9;
        const int rem = idx & 511;
        const float* Ws[4] = {W0, W1, W2, W3};
        transpose_tile(Ws[z], wtl + (size_t)z * 2048 * 1024, 1024, 2048, rem & 31, rem >> 5);
    } else {
        const int idx = b - 10368;          // 16 x 8
        transpose_tile(W_agg, wt_agg, 512, 1024, idx & 15, idx >> 4);
    }
}

// ---------------------------------------------------------------------------
// 256x256 tile GEMM, BK=64, 8 waves (2Mx4N), B-persistent schedule, ONE
// barrier + one vmcnt(0) per K-tile (round-11 schedule: stage issues
// interleaved between ds_read batches, hiding under MFMA).
// VMODE 0: value cols -> f32 Cv; VMODE 1: value cols -> fp16 Cv.
// Cols >= NSPLIT -> bf16 Cg (only if Cg != null).
// If part != null: fused column sum/sumsq partials AND last-block BN finale
// (threadfence + device-scope counter; deterministic reduction order; counter
// self-resets for the next stats GEMM in the stream).
// ---------------------------------------------------------------------------
template <int VMODE>
__global__ __launch_bounds__(512, 2) void gemm256_kernel(const unsigned short* __restrict__ A,
                                                         const unsigned short* __restrict__ BT,
                                                         const float* __restrict__ bias,
                                                         void* __restrict__ Cv,
                                                         unsigned short* __restrict__ Cg,
                                                         int NSPLIT,
                                                         float* __restrict__ part,
                                                         const float* __restrict__ gbn,
                                                         const float* __restrict__ btbn,
                                                         float* __restrict__ gscale,
                                                         float* __restrict__ gshift,
                                                         unsigned int* __restrict__ counter,
                                                         float invM,
                                                         int M, int N, int K) {
    // [buf][half][128 rows][64 cols] bf16 = 4 x 16 KB per matrix
    __shared__ __bf16 Alds[2][2][128 * 64];
    __shared__ __bf16 Blds[2][2][128 * 64];

    const int tid  = threadIdx.x;
    const int lane = tid & 63;
    const int wid  = tid >> 6;
    const int wr   = wid >> 2;   // 0..1 : A-half / row half
    const int wc   = wid & 3;    // 0..3 : 64-col group

    // XCD-aware bijective swizzle (all grids have nwg % 8 == 0)
    const int nbx = N >> 8;
    int w = blockIdx.y * nbx + blockIdx.x;
    const int nwg = (M >> 8) * nbx;
    w = (w & 7) * (nwg >> 3) + (w >> 3);
    const int by = w / nbx;
    const int bx = w - by * nbx;
    const int brow = by << 8;
    const int bcol = bx << 8;

    // staging geometry (pre-swizzled global source, linear LDS dest)
    const int sr = tid >> 3;
    const int sc = (((tid & 7) ^ ((tid >> 3) & 7))) << 3;
    const int so = tid * 16;

    const unsigned short* gA = A + (size_t)brow * K;
    const unsigned short* gB = BT + (size_t)bcol * K;

    auto stage = [&](int buf, int hs /*0:A-lo 1:A-hi 2:B-lo 3:B-hi*/, int kt) {
        const unsigned short* gb = (hs < 2 ? gA + (size_t)(hs * 128) * K
                                           : gB + (size_t)((hs - 2) * 128) * K)
                                   + (size_t)kt * 64;
        char* lb = (char*)(hs < 2 ? &Alds[buf][hs & 1][0] : &Blds[buf][hs & 1][0]);
        gload_lds16(gb + (size_t)sr * K + sc, lb + so);
        gload_lds16(gb + (size_t)(sr + 64) * K + sc, lb + so + 8192);
    };

    f32x4 acc[8][4] = {};
    const int NT = K >> 6;

    const int xorkey = (lane & 7) << 4;
    const int abase  = (lane & 15) * 128 + (lane >> 4) * 16;
    const int bofs   = (wc & 1) * 8192;

    #pragma unroll
    for (int h = 0; h < 4; ++h) stage(0, h, 0);

    for (int T = 0; T < NT; ++T) {
        const int cur = T & 1;
        const char* Ab = (const char*)&Alds[cur][wr][0];
        const char* Bb = (const char*)&Blds[cur][wc >> 1][0];

        // all outstanding loads belong to tile T -> exact drain, then barrier
        asm volatile("s_waitcnt vmcnt(0)" ::: "memory");
        __builtin_amdgcn_s_barrier();

        // ---- phase 0: B (persistent) + A rows 0-3, 32 MFMA ----
        bf16x8 b[4][2], a[4][2];
        #pragma unroll
        for (int n = 0; n < 4; ++n)
            #pragma unroll
            for (int kc = 0; kc < 2; ++kc) {
                const int off = abase + bofs + n * 2048 + kc * 64;
                b[n][kc] = *(const bf16x8*)(Bb + (off ^ xorkey));
            }
        #pragma unroll
        for (int i = 0; i < 4; ++i)
            #pragma unroll
            for (int kc = 0; kc < 2; ++kc) {
                const int off = abase + i * 2048 + kc * 64;
                a[i][kc] = *(const bf16x8*)(Ab + (off ^ xorkey));
            }
        if (T + 1 < NT) { stage(cur ^ 1, 0, T + 1); stage(cur ^ 1, 1, T + 1); }
        __builtin_amdgcn_s_setprio(1);
        #pragma unroll
        for (int i = 0; i < 4; ++i)
            #pragma unroll
            for (int n = 0; n < 4; ++n) {
                acc[i][n] = __builtin_amdgcn_mfma_f32_16x16x32_bf16(a[i][0], b[n][0], acc[i][n], 0, 0, 0);
                acc[i][n] = __builtin_amdgcn_mfma_f32_16x16x32_bf16(a[i][1], b[n][1], acc[i][n], 0, 0, 0);
            }
        __builtin_amdgcn_s_setprio(0);

        // ---- phase 1 (no mid barrier): A rows 4-7, 32 MFMA, B from regs ----
        #pragma unroll
        for (int i = 0; i < 4; ++i)
            #pragma unroll
            for (int kc = 0; kc < 2; ++kc) {
                const int off = abase + (4 + i) * 2048 + kc * 64;
                a[i][kc] = *(const bf16x8*)(Ab + (off ^ xorkey));
            }
        if (T + 1 < NT) { stage(cur ^ 1, 2, T + 1); stage(cur ^ 1, 3, T + 1); }
        __builtin_amdgcn_s_setprio(1);
        #pragma unroll
        for (int i = 0; i < 4; ++i)
            #pragma unroll
            for (int n = 0; n < 4; ++n) {
                acc[4 + i][n] = __builtin_amdgcn_mfma_f32_16x16x32_bf16(a[i][0], b[n][0], acc[4 + i][n], 0, 0, 0);
                acc[4 + i][n] = __builtin_amdgcn_mfma_f32_16x16x32_bf16(a[i][1], b[n][1], acc[4 + i][n], 0, 0, 0);
            }
        __builtin_amdgcn_s_setprio(0);
    }

    // epilogue: C/D layout col = lane&15, row = (lane>>4)*4 + j
    const int crow = brow + wr * 128 + ((lane >> 4) << 2);
    const int ccol = bcol + wc * 64 + (lane & 15);
    const bool isgate = (Cg != nullptr) && (bcol >= NSPLIT);  // block-uniform
    const int NG = N - NSPLIT;
    float s_[4], q_[4];
    #pragma unroll
    for (int n = 0; n < 4; ++n) {
        const int col = ccol + n * 16;
        const float bsv = bias[col];
        s_[n] = 0.f; q_[n] = 0.f;
        #pragma unroll
        for (int m = 0; m < 8; ++m) {
            #pragma unroll
            for (int j = 0; j < 4; ++j) {
                const int row = crow + m * 16 + j;
                const float v = acc[m][n][j] + bsv;
                if (isgate)
                    Cg[(size_t)row * NG + (col - NSPLIT)] = f2b(v);
                else if (VMODE == 0)
                    ((float*)Cv)[(size_t)row * NSPLIT + col] = v;
                else
                    ((unsigned short*)Cv)[(size_t)row * NSPLIT + col] = f2h(v);
                s_[n] += v;
                q_[n] = fmaf(v, v, q_[n]);
            }
        }
    }

    if (part) {
        #pragma unroll
        for (int n = 0; n < 4; ++n) {
            s_[n] += __shfl_xor(s_[n], 16); s_[n] += __shfl_xor(s_[n], 32);
            q_[n] += __shfl_xor(q_[n], 16); q_[n] += __shfl_xor(q_[n], 32);
        }
        float* scr = (float*)&Alds[0][0][0];
        __syncthreads();
        if (lane < 16) {
            #pragma unroll
            for (int n = 0; n < 4; ++n) {
                scr[wr * 512 + (wc * 4 + n) * 16 + lane] = s_[n];
                scr[wr * 512 + 256 + (wc * 4 + n) * 16 + lane] = q_[n];
            }
        }
        __syncthreads();
        if (tid < 256) {
            const int c = tid;
            const float ss = scr[c] + scr[512 + c];
            const float qq = scr[256 + c] + scr[768 + c];
            part[(size_t)(by * 2) * N + bcol + c] = ss;
            part[(size_t)(by * 2 + 1) * N + bcol + c] = qq;
        }

        // ---- last-block BN finale: partials -> scale/shift (deterministic) ----
        __threadfence();  // release our partial writes (agent scope)
        __shared__ unsigned int slast;
        if (tid == 0) {
            const unsigned int old =
                __hip_atomic_fetch_add(counter, 1u, __ATOMIC_ACQ_REL, __HIP_MEMORY_SCOPE_AGENT);
            slast = (old == (unsigned int)(nwg - 1)) ? 1u : 0u;
        }
        __syncthreads();
        if (slast) {
            __threadfence();  // acquire: make all blocks' partials visible
            const int nchunk = M >> 8;
            for (int c = tid; c < N; c += 512) {
                float s = 0.f, q = 0.f;
                for (int k = 0; k < nchunk; ++k) {
                    s += part[(size_t)(k * 2) * N + c];
                    q += part[(size_t)(k * 2 + 1) * N + c];
                }
                const float mm = s * invM;
                const float vv = fmaf(q, invM, -mm * mm);
                const float scv = gbn[c] * rsqrtf(vv + EPS_BN);
                gscale[c] = scv;
                gshift[c] = fmaf(-mm, scv, btbn[c]);
            }
            __threadfence();
            if (tid == 0)
                __hip_atomic_store(counter, 0u, __ATOMIC_RELEASE, __HIP_MEMORY_SCOPE_AGENT);
        }
    }
}

// ---------------------------------------------------------------------------
// Sparsemax (Michelot fixed-point), one wave per row, pure shfl_xor
// ---------------------------------------------------------------------------
__global__ __launch_bounds__(256) void sparsemax_kernel(const unsigned short* __restrict__ hpre,
                                                        const float* __restrict__ prior,
                                                        const float* __restrict__ x,
                                                        const float* __restrict__ scale,
                                                        const float* __restrict__ shift,
                                                        float* __restrict__ mask_o,
                                                        float* __restrict__ newp_o,
                                                        unsigned short* __restrict__ mx_bf) {
    const int lane = threadIdx.x & 63;
    const int row  = blockIdx.x * 4 + (threadIdx.x >> 6);
    const size_t base = (size_t)row * 1024;

    float z[16], p[16];
    float s0 = 0.f;
    #pragma unroll
    for (int j = 0; j < 4; ++j) {
        const int col = j * 256 + lane * 4;
        const float4 pr = *(const float4*)(prior + base + col);
        const ushort4 hp = *(const ushort4*)(hpre + base + col);
        const float4 sc = *(const float4*)(scale + col);
        const float4 sh = *(const float4*)(shift + col);
        p[j * 4 + 0] = pr.x; p[j * 4 + 1] = pr.y; p[j * 4 + 2] = pr.z; p[j * 4 + 3] = pr.w;
        z[j * 4 + 0] = pr.x * fmaf(h2f(hp.x), sc.x, sh.x);
        z[j * 4 + 1] = pr.y * fmaf(h2f(hp.y), sc.y, sh.y);
        z[j * 4 + 2] = pr.z * fmaf(h2f(hp.z), sc.z, sh.z);
        z[j * 4 + 3] = pr.w * fmaf(h2f(hp.w), sc.w, sh.w);
        s0 += z[j * 4 + 0] + z[j * 4 + 1] + z[j * 4 + 2] + z[j * 4 + 3];
    }
    #pragma unroll
    for (int off = 1; off < 64; off <<= 1) s0 += __shfl_xor(s0, off);
    float tau = (s0 - 1.0f) * (1.0f / 1024.0f);

    for (int it = 0; it < 32; ++it) {
        float s = 0.f, c = 0.f;
        #pragma unroll
        for (int j = 0; j < 16; ++j)
            if (z[j] > tau) { s += z[j]; c += 1.f; }
        #pragma unroll
        for (int off = 1; off < 64; off <<= 1) {
            s += __shfl_xor(s, off);
            c += __shfl_xor(c, off);
        }
        const float nt = (s - 1.0f) / c;
        if (nt == tau) break;   // wave-uniform
        tau = nt;
    }

    #pragma unroll
    for (int j = 0; j < 4; ++j) {
        const int col = j * 256 + lane * 4;
        const float4 xv = *(const float4*)(x + base + col);
        float m[4];
        #pragma unroll
        for (int k = 0; k < 4; ++k) m[k] = fmaxf(z[j * 4 + k] - tau, 0.f);
        *(float4*)(mask_o + base + col) = make_float4(m[0], m[1], m[2], m[3]);
        *(float4*)(newp_o + base + col) = make_float4(
            p[j * 4 + 0] * (GAMMA_C - m[0]), p[j * 4 + 1] * (GAMMA_C - m[1]),
            p[j * 4 + 2] * (GAMMA_C - m[2]), p[j * 4 + 3] * (GAMMA_C - m[3]));
        ushort4 q;
        q.x = f2b(m[0] * xv.x); q.y = f2b(m[1] * xv.y);
        q.z = f2b(m[2] * xv.z); q.w = f2b(m[3] * xv.w);
        *(ushort4*)(mx_bf + base + col) = q;
    }
}

// ---------------------------------------------------------------------------
// GLU (layers 1-3): value half fp16 (uv), gate half bf16 (ug).
// Residual bf16 in-place in h (io_bf); add done in f32 registers.
// ---------------------------------------------------------------------------
__global__ __launch_bounds__(256) void glu_kernel(const unsigned short* __restrict__ uv,
                                                  const unsigned short* __restrict__ ug,
                                                  const float* __restrict__ scale,
                                                  const float* __restrict__ shift,
                                                  unsigned short* __restrict__ h,
                                                  int residual) {
    const int i = blockIdx.x * 256 + threadIdx.x;
    const int r = i >> 8;
    const int c = (i & 255) * 4;
    const size_t ob = (size_t)r * 1024 + c;
    const ushort4 ua = *(const ushort4*)(uv + ob);
    const ushort4 ug4 = *(const ushort4*)(ug + ob);
    const float4 sa = *(const float4*)(scale + c);
    const float4 sha = *(const float4*)(shift + c);
    const float4 sb = *(const float4*)(scale + 1024 + c);
    const float4 shb = *(const float4*)(shift + 1024 + c);

    float va[4], vb[4], o[4];
    va[0] = fmaf(h2f(ua.x), sa.x, sha.x); va[1] = fmaf(h2f(ua.y), sa.y, sha.y);
    va[2] = fmaf(h2f(ua.z), sa.z, sha.z); va[3] = fmaf(h2f(ua.w), sa.w, sha.w);
    vb[0] = fmaf(b2f(ug4.x), sb.x, shb.x); vb[1] = fmaf(b2f(ug4.y), sb.y, shb.y);
    vb[2] = fmaf(b2f(ug4.z), sb.z, shb.z); vb[3] = fmaf(b2f(ug4.w), sb.w, shb.w);
    #pragma unroll
    for (int j = 0; j < 4; ++j)
        o[j] = va[j] / (1.f + __expf(-vb[j]));
    if (residual) {
        const ushort4 hv = *(const ushort4*)(h + ob);
        o[0] = (o[0] + b2f(hv.x)) * SQRT_HALF_C;
        o[1] = (o[1] + b2f(hv.y)) * SQRT_HALF_C;
        o[2] = (o[2] + b2f(hv.z)) * SQRT_HALF_C;
        o[3] = (o[3] + b2f(hv.w)) * SQRT_HALF_C;
    }
    ushort4 q;
    q.x = f2b(o[0]); q.y = f2b(o[1]); q.z = f2b(o[2]); q.w = f2b(o[3]);
    *(ushort4*)(h + ob) = q;
}

// ---------------------------------------------------------------------------
// GLU (layer 4) + split: a_out (f32), relu(d) (f32) + bf16 into SEPARATE buf
// value fp16, hprev (h3) bf16
// ---------------------------------------------------------------------------
__global__ __launch_bounds__(256) void glu_final_kernel(const unsigned short* __restrict__ uv,
                                                        const unsigned short* __restrict__ ug,
                                                        const float* __restrict__ scale,
                                                        const float* __restrict__ shift,
                                                        const unsigned short* __restrict__ hprev,
                                                        float* __restrict__ aout,
                                                        float* __restrict__ outp,
                                                        unsigned short* __restrict__ outb) {
    const int i = blockIdx.x * 256 + threadIdx.x;
    const int r = i >> 8;
    const int c = (i & 255) * 4;
    const size_t ob0 = (size_t)r * 1024 + c;
    const ushort4 ua = *(const ushort4*)(uv + ob0);
    const ushort4 ug4 = *(const ushort4*)(ug + ob0);
    const float4 sa = *(const float4*)(scale + c);
    const float4 sha = *(const float4*)(shift + c);
    const float4 sb = *(const float4*)(scale + 1024 + c);
    const float4 shb = *(const float4*)(shift + 1024 + c);

    float va[4], vb[4], o[4];
    va[0] = fmaf(h2f(ua.x), sa.x, sha.x); va[1] = fmaf(h2f(ua.y), sa.y, sha.y);
    va[2] = fmaf(h2f(ua.z), sa.z, sha.z); va[3] = fmaf(h2f(ua.w), sa.w, sha.w);
    vb[0] = fmaf(b2f(ug4.x), sb.x, shb.x); vb[1] = fmaf(b2f(ug4.y), sb.y, shb.y);
    vb[2] = fmaf(b2f(ug4.z), sb.z, shb.z); vb[3] = fmaf(b2f(ug4.w), sb.w, shb.w);
    const ushort4 hv = *(const ushort4*)(hprev + ob0);
    o[0] = (va[0] / (1.f + __expf(-vb[0])) + b2f(hv.x)) * SQRT_HALF_C;
    o[1] = (va[1] / (1.f + __expf(-vb[1])) + b2f(hv.y)) * SQRT_HALF_C;
    o[2] = (va[2] / (1.f + __expf(-vb[2])) + b2f(hv.z)) * SQRT_HALF_C;
    o[3] = (va[3] / (1.f + __expf(-vb[3])) + b2f(hv.w)) * SQRT_HALF_C;

    if (c < 512) {
        o[0] = fmaxf(o[0], 0.f); o[1] = fmaxf(o[1], 0.f);
        o[2] = fmaxf(o[2], 0.f); o[3] = fmaxf(o[3], 0.f);
        const size_t ob = (size_t)r * 512 + c;
        *(float4*)(outp + ob) = make_float4(o[0], o[1], o[2], o[3]);
        ushort4 q;
        q.x = f2b(o[0]); q.y = f2b(o[1]); q.z = f2b(o[2]); q.w = f2b(o[3]);
        *(ushort4*)(outb + ob) = q;
    } else {
        const size_t ob = (size_t)r * 512 + (c - 512);
        *(float4*)(aout + ob) = make_float4(o[0], o[1], o[2], o[3]);
    }
}

// ---------------------------------------------------------------------------
extern "C" void kernel_launch(void* const* d_in, const int* in_sizes, int n_in,
                              void* d_out, int out_size, void* d_ws, size_t ws_size,
                              hipStream_t stream) {
    const float* a      = (const float*)d_in[0];
    const float* x      = (const float*)d_in[1];
    const float* prior  = (const float*)d_in[2];
    const float* W_att  = (const float*)d_in[3];
    const float* b_att  = (const float*)d_in[4];
    const float* g_att  = (const float*)d_in[5];
    const float* bt_att = (const float*)d_in[6];
    const float* Wl[4]  = {(const float*)d_in[7],  (const float*)d_in[11],
                           (const float*)d_in[15], (const float*)d_in[19]};
    const float* bl[4]  = {(const float*)d_in[8],  (const float*)d_in[12],
                           (const float*)d_in[16], (const float*)d_in[20]};
    const float* gl[4]  = {(const float*)d_in[9],  (const float*)d_in[13],
                           (const float*)d_in[17], (const float*)d_in[21]};
    const float* btl[4] = {(const float*)d_in[10], (const float*)d_in[14],
                           (const float*)d_in[18], (const float*)d_in[22]};
    const float* W_agg  = (const float*)d_in[23];
    const float* b_agg  = (const float*)d_in[24];

    constexpr int B = 16384, D = 1024, Na = 512, Nd = 512, H = 1024, H2 = 2048;

    char* wsp = (char*)d_ws;
    auto wsalloc = [&](size_t bytes) {
        void* p = (void*)wsp;
        wsp += (bytes + 255) & ~(size_t)255;
        return p;
    };
    unsigned short* u_hf  = (unsigned short*)wsalloc((size_t)B * H * 2);  // fp16 value half (also hpre)
    unsigned short* u_gbf = (unsigned short*)wsalloc((size_t)B * H * 2);  // gate half (bf16)
    unsigned short* io_bf = (unsigned short*)wsalloc((size_t)B * H * 2);  // masked_x / h (bf16, in-place chain)
    unsigned short* a_bf  = (unsigned short*)wsalloc((size_t)B * Na * 2); // bf16 a, later relu(d)
    unsigned short* wt_att = (unsigned short*)wsalloc((size_t)D * Na * 2);
    unsigned short* wtl    = (unsigned short*)wsalloc((size_t)4 * H2 * D * 2);
    unsigned short* wt_agg = (unsigned short*)wsalloc((size_t)D * Nd * 2);
    float* part   = (float*)wsalloc((size_t)128 * 2 * 2048 * 4);
    float* sscale = (float*)wsalloc(2048 * 4);
    float* sshift = (float*)wsalloc(2048 * 4);
    unsigned int* counter = (unsigned int*)wsalloc(256);

    float* out = (float*)d_out;
    float* aout_o = out;
    float* outp_o = out + (size_t)B * Nd;
    float* mask_o = outp_o + (size_t)B * Na;
    float* agg_o  = mask_o + (size_t)B * D;
    float* newp_o = agg_o + (size_t)B * D;

    // 1. input / weight conversion (single merged launch; zeroes counter)
    convert_all_kernel<<<10496, 256, 0, stream>>>(a, a_bf, W_att, wt_att,
                                                  Wl[0], Wl[1], Wl[2], Wl[3], wtl,
                                                  W_agg, wt_agg, counter);

    // 2. attention GEMM (+fused stats + BN finale, fp16 out) + sparsemax
    gemm256_kernel<1><<<dim3(D / 256, B / 256), 512, 0, stream>>>(
        a_bf, wt_att, b_att, u_hf, nullptr, D,
        part, g_att, bt_att, sscale, sshift, counter, 1.0f / B, B, D, Na);
    sparsemax_kernel<<<B / 4, 256, 0, stream>>>(u_hf, prior, x, sscale, sshift, mask_o, newp_o, io_bf);

    // 3. four GLU blocks (value half fp16, gate half bf16, bf16 residual chain)
    for (int l = 0; l < 4; ++l) {
        gemm256_kernel<1><<<dim3(H2 / 256, B / 256), 512, 0, stream>>>(
            io_bf, wtl + (size_t)l * H2 * D, bl[l], u_hf, u_gbf, H,
            part, gl[l], btl[l], sscale, sshift, counter, 1.0f / B, B, H2, H);
        if (l < 3)
            glu_kernel<<<(B * H / 4) / 256, 256, 0, stream>>>(u_hf, u_gbf, sscale, sshift, io_bf, l > 0);
        else
            glu_final_kernel<<<(B * H / 4) / 256, 256, 0, stream>>>(u_hf, u_gbf, sscale, sshift, io_bf,
                                                                    aout_o, outp_o, a_bf);
    }

    // 4. aggregate GEMM (f32 out, no stats)
    gemm256_kernel<0><<<dim3(D / 256, B / 256), 512, 0, stream>>>(
        a_bf, wt_agg, b_agg, agg_o, nullptr, D,
        nullptr, nullptr, nullptr, nullptr, nullptr, nullptr, 0.f, B, D, Nd);
}

// Round 15
// 623.128 us; speedup vs baseline: 2.4293x; 2.4293x over previous
//
#include <hip/hip_runtime.h>
#include <hip/hip_fp16.h>
#include <stdint.h>

#define SQRT_HALF_C 0.70710678118654752440f
#define GAMMA_C 1.3f
#define EPS_BN 1e-5f

typedef float f32x4 __attribute__((ext_vector_type(4)));
typedef __bf16 bf16x8 __attribute__((ext_vector_type(8)));

__device__ __forceinline__ unsigned short f2b(float f) {
    unsigned int u = __float_as_uint(f);
    unsigned int r = (u + 0x7FFFu + ((u >> 16) & 1u)) >> 16;
    return (unsigned short)r;
}
__device__ __forceinline__ float b2f(unsigned short b) {
    return __uint_as_float((unsigned int)b << 16);
}
__device__ __forceinline__ unsigned short f2h(float f) {
    return __half_as_ushort(__float2half(f));
}
__device__ __forceinline__ float h2f(unsigned short u) {
    return __half2float(__ushort_as_half(u));
}

__device__ __forceinline__ void gload_lds16(const void* g, void* l) {
    __builtin_amdgcn_global_load_lds((__attribute__((address_space(1))) void*)(g),
                                     (__attribute__((address_space(3))) void*)(l),
                                     16, 0, 0);
}

// ---------------------------------------------------------------------------
// Merged input/weight conversion kernel (one launch):
//   blocks [0, 8192)            : a (f32) -> a_bf (bf16), 4 elems/thread
//   blocks [8192, 8320)         : W_att transpose  (K=512,  N=1024)
//   blocks [8320, 10368)        : Wl[0..3] transpose (K=1024, N=2048) x4
//   blocks [10368, 10496)       : W_agg transpose  (K=512,  N=1024)
// ---------------------------------------------------------------------------
__device__ __forceinline__ void transpose_tile(const float* __restrict__ W,
                                               unsigned short* __restrict__ WT,
                                               int K, int N, int bx, int by) {
    __shared__ float t[64][65];
    const int n0 = bx * 64;
    const int k0 = by * 64;
    const int tx = threadIdx.x & 63;
    const int ty = threadIdx.x >> 6;
    #pragma unroll
    for (int i = ty; i < 64; i += 4)
        t[i][tx] = W[(size_t)(k0 + i) * N + n0 + tx];
    __syncthreads();
    #pragma unroll
    for (int i = ty; i < 64; i += 4)
        WT[(size_t)(n0 + i) * K + k0 + tx] = f2b(t[tx][i]);
}

__global__ __launch_bounds__(256) void convert_all_kernel(const float* __restrict__ a,
                                                          unsigned short* __restrict__ a_bf,
                                                          const float* __restrict__ W_att,
                                                          unsigned short* __restrict__ wt_att,
                                                          const float* __restrict__ W0,
                                                          const float* __restrict__ W1,
                                                          const float* __restrict__ W2,
                                                          const float* __restrict__ W3,
                                                          unsigned short* __restrict__ wtl,
                                                          const float* __restrict__ W_agg,
                                                          unsigned short* __restrict__ wt_agg) {
    const int b = blockIdx.x;
    if (b < 8192) {
        const int i = b * 256 + threadIdx.x;
        float4 v = *(const float4*)(a + (size_t)i * 4);
        ushort4 q;
        q.x = f2b(v.x); q.y = f2b(v.y); q.z = f2b(v.z); q.w = f2b(v.w);
        *(ushort4*)(a_bf + (size_t)i * 4) = q;
    } else if (b < 8320) {
        const int idx = b - 8192;           // 16 x 8
        transpose_tile(W_att, wt_att, 512, 1024, idx & 15, idx >> 4);
    } else if (b < 10368) {
        const int idx = b - 8320;           // 4 layers x (32 x 16)
        const int z = idx >> 9;
        const int rem = idx & 511;
        const float* Ws[4] = {W0, W1, W2, W3};
        transpose_tile(Ws[z], wtl + (size_t)z * 2048 * 1024, 1024, 2048, rem & 31, rem >> 5);
    } else {
        const int idx = b - 10368;          // 16 x 8
        transpose_tile(W_agg, wt_agg, 512, 1024, idx & 15, idx >> 4);
    }
}

// ---------------------------------------------------------------------------
// 256x256 tile GEMM, BK=64, 8 waves (2Mx4N), B-persistent schedule, ONE
// barrier + one vmcnt(0) per K-tile (round-11 schedule: stage issues
// interleaved between ds_read batches, hiding under MFMA).
// VMODE 0: value cols -> f32 Cv; VMODE 1: value cols -> fp16 Cv.
// Cols >= NSPLIT -> bf16 Cg (only if Cg != null).
// Optional fused column sum/sumsq partials (per 256-row chunk, exact f32).
// NOTE: no cross-block sync here — device-scope fences flush the non-coherent
// per-XCD L2s and cost ~5x the GEMM time (round-14 lesson).
// ---------------------------------------------------------------------------
template <int VMODE>
__global__ __launch_bounds__(512, 2) void gemm256_kernel(const unsigned short* __restrict__ A,
                                                         const unsigned short* __restrict__ BT,
                                                         const float* __restrict__ bias,
                                                         void* __restrict__ Cv,
                                                         unsigned short* __restrict__ Cg,
                                                         int NSPLIT,
                                                         float* __restrict__ part,
                                                         int M, int N, int K) {
    // [buf][half][128 rows][64 cols] bf16 = 4 x 16 KB per matrix
    __shared__ __bf16 Alds[2][2][128 * 64];
    __shared__ __bf16 Blds[2][2][128 * 64];

    const int tid  = threadIdx.x;
    const int lane = tid & 63;
    const int wid  = tid >> 6;
    const int wr   = wid >> 2;   // 0..1 : A-half / row half
    const int wc   = wid & 3;    // 0..3 : 64-col group

    // XCD-aware bijective swizzle (all grids have nwg % 8 == 0)
    const int nbx = N >> 8;
    int w = blockIdx.y * nbx + blockIdx.x;
    const int nwg = (M >> 8) * nbx;
    w = (w & 7) * (nwg >> 3) + (w >> 3);
    const int by = w / nbx;
    const int bx = w - by * nbx;
    const int brow = by << 8;
    const int bcol = bx << 8;

    // staging geometry (pre-swizzled global source, linear LDS dest)
    const int sr = tid >> 3;
    const int sc = (((tid & 7) ^ ((tid >> 3) & 7))) << 3;
    const int so = tid * 16;

    const unsigned short* gA = A + (size_t)brow * K;
    const unsigned short* gB = BT + (size_t)bcol * K;

    auto stage = [&](int buf, int hs /*0:A-lo 1:A-hi 2:B-lo 3:B-hi*/, int kt) {
        const unsigned short* gb = (hs < 2 ? gA + (size_t)(hs * 128) * K
                                           : gB + (size_t)((hs - 2) * 128) * K)
                                   + (size_t)kt * 64;
        char* lb = (char*)(hs < 2 ? &Alds[buf][hs & 1][0] : &Blds[buf][hs & 1][0]);
        gload_lds16(gb + (size_t)sr * K + sc, lb + so);
        gload_lds16(gb + (size_t)(sr + 64) * K + sc, lb + so + 8192);
    };

    f32x4 acc[8][4] = {};
    const int NT = K >> 6;

    const int xorkey = (lane & 7) << 4;
    const int abase  = (lane & 15) * 128 + (lane >> 4) * 16;
    const int bofs   = (wc & 1) * 8192;

    #pragma unroll
    for (int h = 0; h < 4; ++h) stage(0, h, 0);

    for (int T = 0; T < NT; ++T) {
        const int cur = T & 1;
        const char* Ab = (const char*)&Alds[cur][wr][0];
        const char* Bb = (const char*)&Blds[cur][wc >> 1][0];

        // all outstanding loads belong to tile T -> exact drain, then barrier
        asm volatile("s_waitcnt vmcnt(0)" ::: "memory");
        __builtin_amdgcn_s_barrier();

        // ---- phase 0: B (persistent) + A rows 0-3, 32 MFMA ----
        bf16x8 b[4][2], a[4][2];
        #pragma unroll
        for (int n = 0; n < 4; ++n)
            #pragma unroll
            for (int kc = 0; kc < 2; ++kc) {
                const int off = abase + bofs + n * 2048 + kc * 64;
                b[n][kc] = *(const bf16x8*)(Bb + (off ^ xorkey));
            }
        #pragma unroll
        for (int i = 0; i < 4; ++i)
            #pragma unroll
            for (int kc = 0; kc < 2; ++kc) {
                const int off = abase + i * 2048 + kc * 64;
                a[i][kc] = *(const bf16x8*)(Ab + (off ^ xorkey));
            }
        if (T + 1 < NT) { stage(cur ^ 1, 0, T + 1); stage(cur ^ 1, 1, T + 1); }
        __builtin_amdgcn_s_setprio(1);
        #pragma unroll
        for (int i = 0; i < 4; ++i)
            #pragma unroll
            for (int n = 0; n < 4; ++n) {
                acc[i][n] = __builtin_amdgcn_mfma_f32_16x16x32_bf16(a[i][0], b[n][0], acc[i][n], 0, 0, 0);
                acc[i][n] = __builtin_amdgcn_mfma_f32_16x16x32_bf16(a[i][1], b[n][1], acc[i][n], 0, 0, 0);
            }
        __builtin_amdgcn_s_setprio(0);

        // ---- phase 1 (no mid barrier): A rows 4-7, 32 MFMA, B from regs ----
        #pragma unroll
        for (int i = 0; i < 4; ++i)
            #pragma unroll
            for (int kc = 0; kc < 2; ++kc) {
                const int off = abase + (4 + i) * 2048 + kc * 64;
                a[i][kc] = *(const bf16x8*)(Ab + (off ^ xorkey));
            }
        if (T + 1 < NT) { stage(cur ^ 1, 2, T + 1); stage(cur ^ 1, 3, T + 1); }
        __builtin_amdgcn_s_setprio(1);
        #pragma unroll
        for (int i = 0; i < 4; ++i)
            #pragma unroll
            for (int n = 0; n < 4; ++n) {
                acc[4 + i][n] = __builtin_amdgcn_mfma_f32_16x16x32_bf16(a[i][0], b[n][0], acc[4 + i][n], 0, 0, 0);
                acc[4 + i][n] = __builtin_amdgcn_mfma_f32_16x16x32_bf16(a[i][1], b[n][1], acc[4 + i][n], 0, 0, 0);
            }
        __builtin_amdgcn_s_setprio(0);
    }

    // epilogue: C/D layout col = lane&15, row = (lane>>4)*4 + j
    const int crow = brow + wr * 128 + ((lane >> 4) << 2);
    const int ccol = bcol + wc * 64 + (lane & 15);
    const bool isgate = (Cg != nullptr) && (bcol >= NSPLIT);  // block-uniform
    const int NG = N - NSPLIT;
    float s_[4], q_[4];
    #pragma unroll
    for (int n = 0; n < 4; ++n) {
        const int col = ccol + n * 16;
        const float bsv = bias[col];
        s_[n] = 0.f; q_[n] = 0.f;
        #pragma unroll
        for (int m = 0; m < 8; ++m) {
            #pragma unroll
            for (int j = 0; j < 4; ++j) {
                const int row = crow + m * 16 + j;
                const float v = acc[m][n][j] + bsv;
                if (isgate)
                    Cg[(size_t)row * NG + (col - NSPLIT)] = f2b(v);
                else if (VMODE == 0)
                    ((float*)Cv)[(size_t)row * NSPLIT + col] = v;
                else
                    ((unsigned short*)Cv)[(size_t)row * NSPLIT + col] = f2h(v);
                s_[n] += v;
                q_[n] = fmaf(v, v, q_[n]);
            }
        }
    }

    if (part) {
        #pragma unroll
        for (int n = 0; n < 4; ++n) {
            s_[n] += __shfl_xor(s_[n], 16); s_[n] += __shfl_xor(s_[n], 32);
            q_[n] += __shfl_xor(q_[n], 16); q_[n] += __shfl_xor(q_[n], 32);
        }
        float* scr = (float*)&Alds[0][0][0];
        __syncthreads();
        if (lane < 16) {
            #pragma unroll
            for (int n = 0; n < 4; ++n) {
                scr[wr * 512 + (wc * 4 + n) * 16 + lane] = s_[n];
                scr[wr * 512 + 256 + (wc * 4 + n) * 16 + lane] = q_[n];
            }
        }
        __syncthreads();
        if (tid < 256) {
            const int c = tid;
            const float ss = scr[c] + scr[512 + c];
            const float qq = scr[256 + c] + scr[768 + c];
            part[(size_t)(by * 2) * N + bcol + c] = ss;
            part[(size_t)(by * 2 + 1) * N + bcol + c] = qq;
        }
    }
}

// ---------------------------------------------------------------------------
// BN stats final reduce: combine per-block-row partials -> scale/shift
// ---------------------------------------------------------------------------
__global__ __launch_bounds__(256) void bnstats2_kernel(const float* __restrict__ part,
                                                       const float* __restrict__ g,
                                                       const float* __restrict__ bt,
                                                       float* __restrict__ scale,
                                                       float* __restrict__ shift,
                                                       int N, int nchunk, float invM) {
    const int tx = threadIdx.x & 63;
    const int ty = threadIdx.x >> 6;
    const int c = blockIdx.x * 64 + tx;
    float s = 0.f, q = 0.f;
    for (int k = ty; k < nchunk; k += 4) {
        s += part[(size_t)(k * 2) * N + c];
        q += part[(size_t)(k * 2 + 1) * N + c];
    }
    __shared__ float sm[2][4][64];
    sm[0][ty][tx] = s;
    sm[1][ty][tx] = q;
    __syncthreads();
    if (ty == 0) {
        s = sm[0][0][tx] + sm[0][1][tx] + sm[0][2][tx] + sm[0][3][tx];
        q = sm[1][0][tx] + sm[1][1][tx] + sm[1][2][tx] + sm[1][3][tx];
        const float m = s * invM;
        const float v = fmaf(q, invM, -m * m);
        const float sc = g[c] * rsqrtf(v + EPS_BN);
        scale[c] = sc;
        shift[c] = fmaf(-m, sc, bt[c]);
    }
}

// ---------------------------------------------------------------------------
// Sparsemax (Michelot fixed-point), one wave per row, pure shfl_xor
// ---------------------------------------------------------------------------
__global__ __launch_bounds__(256) void sparsemax_kernel(const unsigned short* __restrict__ hpre,
                                                        const float* __restrict__ prior,
                                                        const float* __restrict__ x,
                                                        const float* __restrict__ scale,
                                                        const float* __restrict__ shift,
                                                        float* __restrict__ mask_o,
                                                        float* __restrict__ newp_o,
                                                        unsigned short* __restrict__ mx_bf) {
    const int lane = threadIdx.x & 63;
    const int row  = blockIdx.x * 4 + (threadIdx.x >> 6);
    const size_t base = (size_t)row * 1024;

    float z[16], p[16];
    float s0 = 0.f;
    #pragma unroll
    for (int j = 0; j < 4; ++j) {
        const int col = j * 256 + lane * 4;
        const float4 pr = *(const float4*)(prior + base + col);
        const ushort4 hp = *(const ushort4*)(hpre + base + col);
        const float4 sc = *(const float4*)(scale + col);
        const float4 sh = *(const float4*)(shift + col);
        p[j * 4 + 0] = pr.x; p[j * 4 + 1] = pr.y; p[j * 4 + 2] = pr.z; p[j * 4 + 3] = pr.w;
        z[j * 4 + 0] = pr.x * fmaf(h2f(hp.x), sc.x, sh.x);
        z[j * 4 + 1] = pr.y * fmaf(h2f(hp.y), sc.y, sh.y);
        z[j * 4 + 2] = pr.z * fmaf(h2f(hp.z), sc.z, sh.z);
        z[j * 4 + 3] = pr.w * fmaf(h2f(hp.w), sc.w, sh.w);
        s0 += z[j * 4 + 0] + z[j * 4 + 1] + z[j * 4 + 2] + z[j * 4 + 3];
    }
    #pragma unroll
    for (int off = 1; off < 64; off <<= 1) s0 += __shfl_xor(s0, off);
    float tau = (s0 - 1.0f) * (1.0f / 1024.0f);

    for (int it = 0; it < 32; ++it) {
        float s = 0.f, c = 0.f;
        #pragma unroll
        for (int j = 0; j < 16; ++j)
            if (z[j] > tau) { s += z[j]; c += 1.f; }
        #pragma unroll
        for (int off = 1; off < 64; off <<= 1) {
            s += __shfl_xor(s, off);
            c += __shfl_xor(c, off);
        }
        const float nt = (s - 1.0f) / c;
        if (nt == tau) break;   // wave-uniform
        tau = nt;
    }

    #pragma unroll
    for (int j = 0; j < 4; ++j) {
        const int col = j * 256 + lane * 4;
        const float4 xv = *(const float4*)(x + base + col);
        float m[4];
        #pragma unroll
        for (int k = 0; k < 4; ++k) m[k] = fmaxf(z[j * 4 + k] - tau, 0.f);
        *(float4*)(mask_o + base + col) = make_float4(m[0], m[1], m[2], m[3]);
        *(float4*)(newp_o + base + col) = make_float4(
            p[j * 4 + 0] * (GAMMA_C - m[0]), p[j * 4 + 1] * (GAMMA_C - m[1]),
            p[j * 4 + 2] * (GAMMA_C - m[2]), p[j * 4 + 3] * (GAMMA_C - m[3]));
        ushort4 q;
        q.x = f2b(m[0] * xv.x); q.y = f2b(m[1] * xv.y);
        q.z = f2b(m[2] * xv.z); q.w = f2b(m[3] * xv.w);
        *(ushort4*)(mx_bf + base + col) = q;
    }
}

// ---------------------------------------------------------------------------
// GLU (layers 1-3): value half fp16 (uv), gate half bf16 (ug).
// Residual bf16 in-place in h (io_bf); add done in f32 registers.
// ---------------------------------------------------------------------------
__global__ __launch_bounds__(256) void glu_kernel(const unsigned short* __restrict__ uv,
                                                  const unsigned short* __restrict__ ug,
                                                  const float* __restrict__ scale,
                                                  const float* __restrict__ shift,
                                                  unsigned short* __restrict__ h,
                                                  int residual) {
    const int i = blockIdx.x * 256 + threadIdx.x;
    const int r = i >> 8;
    const int c = (i & 255) * 4;
    const size_t ob = (size_t)r * 1024 + c;
    const ushort4 ua = *(const ushort4*)(uv + ob);
    const ushort4 ug4 = *(const ushort4*)(ug + ob);
    const float4 sa = *(const float4*)(scale + c);
    const float4 sha = *(const float4*)(shift + c);
    const float4 sb = *(const float4*)(scale + 1024 + c);
    const float4 shb = *(const float4*)(shift + 1024 + c);

    float va[4], vb[4], o[4];
    va[0] = fmaf(h2f(ua.x), sa.x, sha.x); va[1] = fmaf(h2f(ua.y), sa.y, sha.y);
    va[2] = fmaf(h2f(ua.z), sa.z, sha.z); va[3] = fmaf(h2f(ua.w), sa.w, sha.w);
    vb[0] = fmaf(b2f(ug4.x), sb.x, shb.x); vb[1] = fmaf(b2f(ug4.y), sb.y, shb.y);
    vb[2] = fmaf(b2f(ug4.z), sb.z, shb.z); vb[3] = fmaf(b2f(ug4.w), sb.w, shb.w);
    #pragma unroll
    for (int j = 0; j < 4; ++j)
        o[j] = va[j] / (1.f + __expf(-vb[j]));
    if (residual) {
        const ushort4 hv = *(const ushort4*)(h + ob);
        o[0] = (o[0] + b2f(hv.x)) * SQRT_HALF_C;
        o[1] = (o[1] + b2f(hv.y)) * SQRT_HALF_C;
        o[2] = (o[2] + b2f(hv.z)) * SQRT_HALF_C;
        o[3] = (o[3] + b2f(hv.w)) * SQRT_HALF_C;
    }
    ushort4 q;
    q.x = f2b(o[0]); q.y = f2b(o[1]); q.z = f2b(o[2]); q.w = f2b(o[3]);
    *(ushort4*)(h + ob) = q;
}

// ---------------------------------------------------------------------------
// GLU (layer 4) + split: a_out (f32), relu(d) (f32) + bf16 into SEPARATE buf
// value fp16, hprev (h3) bf16
// ---------------------------------------------------------------------------
__global__ __launch_bounds__(256) void glu_final_kernel(const unsigned short* __restrict__ uv,
                                                        const unsigned short* __restrict__ ug,
                                                        const float* __restrict__ scale,
                                                        const float* __restrict__ shift,
                                                        const unsigned short* __restrict__ hprev,
                                                        float* __restrict__ aout,
                                                        float* __restrict__ outp,
                                                        unsigned short* __restrict__ outb) {
    const int i = blockIdx.x * 256 + threadIdx.x;
    const int r = i >> 8;
    const int c = (i & 255) * 4;
    const size_t ob0 = (size_t)r * 1024 + c;
    const ushort4 ua = *(const ushort4*)(uv + ob0);
    const ushort4 ug4 = *(const ushort4*)(ug + ob0);
    const float4 sa = *(const float4*)(scale + c);
    const float4 sha = *(const float4*)(shift + c);
    const float4 sb = *(const float4*)(scale + 1024 + c);
    const float4 shb = *(const float4*)(shift + 1024 + c);

    float va[4], vb[4], o[4];
    va[0] = fmaf(h2f(ua.x), sa.x, sha.x); va[1] = fmaf(h2f(ua.y), sa.y, sha.y);
    va[2] = fmaf(h2f(ua.z), sa.z, sha.z); va[3] = fmaf(h2f(ua.w), sa.w, sha.w);
    vb[0] = fmaf(b2f(ug4.x), sb.x, shb.x); vb[1] = fmaf(b2f(ug4.y), sb.y, shb.y);
    vb[2] = fmaf(b2f(ug4.z), sb.z, shb.z); vb[3] = fmaf(b2f(ug4.w), sb.w, shb.w);
    const ushort4 hv = *(const ushort4*)(hprev + ob0);
    o[0] = (va[0] / (1.f + __expf(-vb[0])) + b2f(hv.x)) * SQRT_HALF_C;
    o[1] = (va[1] / (1.f + __expf(-vb[1])) + b2f(hv.y)) * SQRT_HALF_C;
    o[2] = (va[2] / (1.f + __expf(-vb[2])) + b2f(hv.z)) * SQRT_HALF_C;
    o[3] = (va[3] / (1.f + __expf(-vb[3])) + b2f(hv.w)) * SQRT_HALF_C;

    if (c < 512) {
        o[0] = fmaxf(o[0], 0.f); o[1] = fmaxf(o[1], 0.f);
        o[2] = fmaxf(o[2], 0.f); o[3] = fmaxf(o[3], 0.f);
        const size_t ob = (size_t)r * 512 + c;
        *(float4*)(outp + ob) = make_float4(o[0], o[1], o[2], o[3]);
        ushort4 q;
        q.x = f2b(o[0]); q.y = f2b(o[1]); q.z = f2b(o[2]); q.w = f2b(o[3]);
        *(ushort4*)(outb + ob) = q;
    } else {
        const size_t ob = (size_t)r * 512 + (c - 512);
        *(float4*)(aout + ob) = make_float4(o[0], o[1], o[2], o[3]);
    }
}

// ---------------------------------------------------------------------------
extern "C" void kernel_launch(void* const* d_in, const int* in_sizes, int n_in,
                              void* d_out, int out_size, void* d_ws, size_t ws_size,
                              hipStream_t stream) {
    const float* a      = (const float*)d_in[0];
    const float* x      = (const float*)d_in[1];
    const float* prior  = (const float*)d_in[2];
    const float* W_att  = (const float*)d_in[3];
    const float* b_att  = (const float*)d_in[4];
    const float* g_att  = (const float*)d_in[5];
    const float* bt_att = (const float*)d_in[6];
    const float* Wl[4]  = {(const float*)d_in[7],  (const float*)d_in[11],
                           (const float*)d_in[15], (const float*)d_in[19]};
    const float* bl[4]  = {(const float*)d_in[8],  (const float*)d_in[12],
                           (const float*)d_in[16], (const float*)d_in[20]};
    const float* gl[4]  = {(const float*)d_in[9],  (const float*)d_in[13],
                           (const float*)d_in[17], (const float*)d_in[21]};
    const float* btl[4] = {(const float*)d_in[10], (const float*)d_in[14],
                           (const float*)d_in[18], (const float*)d_in[22]};
    const float* W_agg  = (const float*)d_in[23];
    const float* b_agg  = (const float*)d_in[24];

    constexpr int B = 16384, D = 1024, Na = 512, Nd = 512, H = 1024, H2 = 2048;

    char* wsp = (char*)d_ws;
    auto wsalloc = [&](size_t bytes) {
        void* p = (void*)wsp;
        wsp += (bytes + 255) & ~(size_t)255;
        return p;
    };
    unsigned short* u_hf  = (unsigned short*)wsalloc((size_t)B * H * 2);  // fp16 value half (also hpre)
    unsigned short* u_gbf = (unsigned short*)wsalloc((size_t)B * H * 2);  // gate half (bf16)
    unsigned short* io_bf = (unsigned short*)wsalloc((size_t)B * H * 2);  // masked_x / h (bf16, in-place chain)
    unsigned short* a_bf  = (unsigned short*)wsalloc((size_t)B * Na * 2); // bf16 a, later relu(d)
    unsigned short* wt_att = (unsigned short*)wsalloc((size_t)D * Na * 2);
    unsigned short* wtl    = (unsigned short*)wsalloc((size_t)4 * H2 * D * 2);
    unsigned short* wt_agg = (unsigned short*)wsalloc((size_t)D * Nd * 2);
    float* part   = (float*)wsalloc((size_t)128 * 2 * 2048 * 4);
    float* sscale = (float*)wsalloc(2048 * 4);
    float* sshift = (float*)wsalloc(2048 * 4);

    float* out = (float*)d_out;
    float* aout_o = out;
    float* outp_o = out + (size_t)B * Nd;
    float* mask_o = outp_o + (size_t)B * Na;
    float* agg_o  = mask_o + (size_t)B * D;
    float* newp_o = agg_o + (size_t)B * D;

    // 1. input / weight conversion (single merged launch)
    convert_all_kernel<<<10496, 256, 0, stream>>>(a, a_bf, W_att, wt_att,
                                                  Wl[0], Wl[1], Wl[2], Wl[3], wtl,
                                                  W_agg, wt_agg);

    // 2. attention GEMM (+fused stats, fp16 out) + BN reduce + sparsemax
    gemm256_kernel<1><<<dim3(D / 256, B / 256), 512, 0, stream>>>(a_bf, wt_att, b_att,
                                                                  u_hf, nullptr, D, part, B, D, Na);
    bnstats2_kernel<<<dim3(D / 64), 256, 0, stream>>>(part, g_att, bt_att, sscale, sshift, D, B / 256, 1.0f / B);
    sparsemax_kernel<<<B / 4, 256, 0, stream>>>(u_hf, prior, x, sscale, sshift, mask_o, newp_o, io_bf);

    // 3. four GLU blocks (value half fp16, gate half bf16, bf16 residual chain)
    for (int l = 0; l < 4; ++l) {
        gemm256_kernel<1><<<dim3(H2 / 256, B / 256), 512, 0, stream>>>(io_bf, wtl + (size_t)l * H2 * D, bl[l],
                                                                       u_hf, u_gbf, H, part, B, H2, H);
        bnstats2_kernel<<<dim3(H2 / 64), 256, 0, stream>>>(part, gl[l], btl[l], sscale, sshift, H2, B / 256, 1.0f / B);
        if (l < 3)
            glu_kernel<<<(B * H / 4) / 256, 256, 0, stream>>>(u_hf, u_gbf, sscale, sshift, io_bf, l > 0);
        else
            glu_final_kernel<<<(B * H / 4) / 256, 256, 0, stream>>>(u_hf, u_gbf, sscale, sshift, io_bf,
                                                                    aout_o, outp_o, a_bf);
    }

    // 4. aggregate GEMM (f32 out, no stats)
    gemm256_kernel<0><<<dim3(D / 256, B / 256), 512, 0, stream>>>(a_bf, wt_agg, b_agg,
                                                                  agg_o, nullptr, D, nullptr, B, D, Nd);
}

// Round 16
// 612.492 us; speedup vs baseline: 2.4715x; 1.0174x over previous
//
#include <hip/hip_runtime.h>
#include <hip/hip_fp16.h>
#include <stdint.h>

#define SQRT_HALF_C 0.70710678118654752440f
#define GAMMA_C 1.3f
#define EPS_BN 1e-5f

typedef float f32x4 __attribute__((ext_vector_type(4)));
typedef __bf16 bf16x8 __attribute__((ext_vector_type(8)));
typedef unsigned short u16x8 __attribute__((ext_vector_type(8)));

__device__ __forceinline__ unsigned short f2b(float f) {
    unsigned int u = __float_as_uint(f);
    unsigned int r = (u + 0x7FFFu + ((u >> 16) & 1u)) >> 16;
    return (unsigned short)r;
}
__device__ __forceinline__ float b2f(unsigned short b) {
    return __uint_as_float((unsigned int)b << 16);
}
__device__ __forceinline__ unsigned short f2h(float f) {
    return __half_as_ushort(__float2half(f));
}
__device__ __forceinline__ float h2f(unsigned short u) {
    return __half2float(__ushort_as_half(u));
}

__device__ __forceinline__ void gload_lds16(const void* g, void* l) {
    __builtin_amdgcn_global_load_lds((__attribute__((address_space(1))) void*)(g),
                                     (__attribute__((address_space(3))) void*)(l),
                                     16, 0, 0);
}

// ---------------------------------------------------------------------------
// Merged input/weight conversion kernel (one launch)
// ---------------------------------------------------------------------------
__device__ __forceinline__ void transpose_tile(const float* __restrict__ W,
                                               unsigned short* __restrict__ WT,
                                               int K, int N, int bx, int by) {
    __shared__ float t[64][65];
    const int n0 = bx * 64;
    const int k0 = by * 64;
    const int tx = threadIdx.x & 63;
    const int ty = threadIdx.x >> 6;
    #pragma unroll
    for (int i = ty; i < 64; i += 4)
        t[i][tx] = W[(size_t)(k0 + i) * N + n0 + tx];
    __syncthreads();
    #pragma unroll
    for (int i = ty; i < 64; i += 4)
        WT[(size_t)(n0 + i) * K + k0 + tx] = f2b(t[tx][i]);
}

__global__ __launch_bounds__(256) void convert_all_kernel(const float* __restrict__ a,
                                                          unsigned short* __restrict__ a_bf,
                                                          const float* __restrict__ W_att,
                                                          unsigned short* __restrict__ wt_att,
                                                          const float* __restrict__ W0,
                                                          const float* __restrict__ W1,
                                                          const float* __restrict__ W2,
                                                          const float* __restrict__ W3,
                                                          unsigned short* __restrict__ wtl,
                                                          const float* __restrict__ W_agg,
                                                          unsigned short* __restrict__ wt_agg) {
    const int b = blockIdx.x;
    if (b < 8192) {
        const int i = b * 256 + threadIdx.x;
        float4 v = *(const float4*)(a + (size_t)i * 4);
        ushort4 q;
        q.x = f2b(v.x); q.y = f2b(v.y); q.z = f2b(v.z); q.w = f2b(v.w);
        *(ushort4*)(a_bf + (size_t)i * 4) = q;
    } else if (b < 8320) {
        const int idx = b - 8192;           // 16 x 8
        transpose_tile(W_att, wt_att, 512, 1024, idx & 15, idx >> 4);
    } else if (b < 10368) {
        const int idx = b - 8320;           // 4 layers x (32 x 16)
        const int z = idx >> 9;
        const int rem = idx & 511;
        const float* Ws[4] = {W0, W1, W2, W3};
        transpose_tile(Ws[z], wtl + (size_t)z * 2048 * 1024, 1024, 2048, rem & 31, rem >> 5);
    } else {
        const int idx = b - 10368;          // 16 x 8
        transpose_tile(W_agg, wt_agg, 512, 1024, idx & 15, idx >> 4);
    }
}

// ---------------------------------------------------------------------------
// 256x256 tile GEMM, BK=64, 8 waves (2Mx4N), B-persistent schedule, ONE
// barrier + one vmcnt(0) per K-tile (round-11 schedule: stage issues
// interleaved between ds_read batches, hiding under MFMA).
// VMODE 0: value cols -> f32 Cv; VMODE 1: value cols -> fp16 Cv.
// Cols >= NSPLIT -> bf16 Cg (only if Cg != null).
// Optional fused column sum/sumsq partials (per 256-row chunk, exact f32).
// NOTE: no cross-block sync here — device-scope fences flush the non-coherent
// per-XCD L2s and cost ~5x the GEMM time (round-14 lesson).
// ---------------------------------------------------------------------------
template <int VMODE>
__global__ __launch_bounds__(512, 2) void gemm256_kernel(const unsigned short* __restrict__ A,
                                                         const unsigned short* __restrict__ BT,
                                                         const float* __restrict__ bias,
                                                         void* __restrict__ Cv,
                                                         unsigned short* __restrict__ Cg,
                                                         int NSPLIT,
                                                         float* __restrict__ part,
                                                         int M, int N, int K) {
    __shared__ __bf16 Alds[2][2][128 * 64];
    __shared__ __bf16 Blds[2][2][128 * 64];

    const int tid  = threadIdx.x;
    const int lane = tid & 63;
    const int wid  = tid >> 6;
    const int wr   = wid >> 2;   // 0..1 : A-half / row half
    const int wc   = wid & 3;    // 0..3 : 64-col group

    // XCD-aware bijective swizzle (all grids have nwg % 8 == 0)
    const int nbx = N >> 8;
    int w = blockIdx.y * nbx + blockIdx.x;
    const int nwg = (M >> 8) * nbx;
    w = (w & 7) * (nwg >> 3) + (w >> 3);
    const int by = w / nbx;
    const int bx = w - by * nbx;
    const int brow = by << 8;
    const int bcol = bx << 8;

    // staging geometry (pre-swizzled global source, linear LDS dest)
    const int sr = tid >> 3;
    const int sc = (((tid & 7) ^ ((tid >> 3) & 7))) << 3;
    const int so = tid * 16;

    const unsigned short* gA = A + (size_t)brow * K;
    const unsigned short* gB = BT + (size_t)bcol * K;

    auto stage = [&](int buf, int hs /*0:A-lo 1:A-hi 2:B-lo 3:B-hi*/, int kt) {
        const unsigned short* gb = (hs < 2 ? gA + (size_t)(hs * 128) * K
                                           : gB + (size_t)((hs - 2) * 128) * K)
                                   + (size_t)kt * 64;
        char* lb = (char*)(hs < 2 ? &Alds[buf][hs & 1][0] : &Blds[buf][hs & 1][0]);
        gload_lds16(gb + (size_t)sr * K + sc, lb + so);
        gload_lds16(gb + (size_t)(sr + 64) * K + sc, lb + so + 8192);
    };

    f32x4 acc[8][4] = {};
    const int NT = K >> 6;

    const int xorkey = (lane & 7) << 4;
    const int abase  = (lane & 15) * 128 + (lane >> 4) * 16;
    const int bofs   = (wc & 1) * 8192;

    #pragma unroll
    for (int h = 0; h < 4; ++h) stage(0, h, 0);

    for (int T = 0; T < NT; ++T) {
        const int cur = T & 1;
        const char* Ab = (const char*)&Alds[cur][wr][0];
        const char* Bb = (const char*)&Blds[cur][wc >> 1][0];

        asm volatile("s_waitcnt vmcnt(0)" ::: "memory");
        __builtin_amdgcn_s_barrier();

        // ---- phase 0: B (persistent) + A rows 0-3, 32 MFMA ----
        bf16x8 b[4][2], a[4][2];
        #pragma unroll
        for (int n = 0; n < 4; ++n)
            #pragma unroll
            for (int kc = 0; kc < 2; ++kc) {
                const int off = abase + bofs + n * 2048 + kc * 64;
                b[n][kc] = *(const bf16x8*)(Bb + (off ^ xorkey));
            }
        #pragma unroll
        for (int i = 0; i < 4; ++i)
            #pragma unroll
            for (int kc = 0; kc < 2; ++kc) {
                const int off = abase + i * 2048 + kc * 64;
                a[i][kc] = *(const bf16x8*)(Ab + (off ^ xorkey));
            }
        if (T + 1 < NT) { stage(cur ^ 1, 0, T + 1); stage(cur ^ 1, 1, T + 1); }
        __builtin_amdgcn_s_setprio(1);
        #pragma unroll
        for (int i = 0; i < 4; ++i)
            #pragma unroll
            for (int n = 0; n < 4; ++n) {
                acc[i][n] = __builtin_amdgcn_mfma_f32_16x16x32_bf16(a[i][0], b[n][0], acc[i][n], 0, 0, 0);
                acc[i][n] = __builtin_amdgcn_mfma_f32_16x16x32_bf16(a[i][1], b[n][1], acc[i][n], 0, 0, 0);
            }
        __builtin_amdgcn_s_setprio(0);

        // ---- phase 1 (no mid barrier): A rows 4-7, 32 MFMA, B from regs ----
        #pragma unroll
        for (int i = 0; i < 4; ++i)
            #pragma unroll
            for (int kc = 0; kc < 2; ++kc) {
                const int off = abase + (4 + i) * 2048 + kc * 64;
                a[i][kc] = *(const bf16x8*)(Ab + (off ^ xorkey));
            }
        if (T + 1 < NT) { stage(cur ^ 1, 2, T + 1); stage(cur ^ 1, 3, T + 1); }
        __builtin_amdgcn_s_setprio(1);
        #pragma unroll
        for (int i = 0; i < 4; ++i)
            #pragma unroll
            for (int n = 0; n < 4; ++n) {
                acc[4 + i][n] = __builtin_amdgcn_mfma_f32_16x16x32_bf16(a[i][0], b[n][0], acc[4 + i][n], 0, 0, 0);
                acc[4 + i][n] = __builtin_amdgcn_mfma_f32_16x16x32_bf16(a[i][1], b[n][1], acc[4 + i][n], 0, 0, 0);
            }
        __builtin_amdgcn_s_setprio(0);
    }

    // epilogue: C/D layout col = lane&15, row = (lane>>4)*4 + j
    const int crow = brow + wr * 128 + ((lane >> 4) << 2);
    const int ccol = bcol + wc * 64 + (lane & 15);
    const bool isgate = (Cg != nullptr) && (bcol >= NSPLIT);  // block-uniform
    const int NG = N - NSPLIT;
    float s_[4], q_[4];
    #pragma unroll
    for (int n = 0; n < 4; ++n) {
        const int col = ccol + n * 16;
        const float bsv = bias[col];
        s_[n] = 0.f; q_[n] = 0.f;
        #pragma unroll
        for (int m = 0; m < 8; ++m) {
            #pragma unroll
            for (int j = 0; j < 4; ++j) {
                const int row = crow + m * 16 + j;
                const float v = acc[m][n][j] + bsv;
                if (isgate)
                    Cg[(size_t)row * NG + (col - NSPLIT)] = f2b(v);
                else if (VMODE == 0)
                    ((float*)Cv)[(size_t)row * NSPLIT + col] = v;
                else
                    ((unsigned short*)Cv)[(size_t)row * NSPLIT + col] = f2h(v);
                s_[n] += v;
                q_[n] = fmaf(v, v, q_[n]);
            }
        }
    }

    if (part) {
        #pragma unroll
        for (int n = 0; n < 4; ++n) {
            s_[n] += __shfl_xor(s_[n], 16); s_[n] += __shfl_xor(s_[n], 32);
            q_[n] += __shfl_xor(q_[n], 16); q_[n] += __shfl_xor(q_[n], 32);
        }
        float* scr = (float*)&Alds[0][0][0];
        __syncthreads();
        if (lane < 16) {
            #pragma unroll
            for (int n = 0; n < 4; ++n) {
                scr[wr * 512 + (wc * 4 + n) * 16 + lane] = s_[n];
                scr[wr * 512 + 256 + (wc * 4 + n) * 16 + lane] = q_[n];
            }
        }
        __syncthreads();
        if (tid < 256) {
            const int c = tid;
            const float ss = scr[c] + scr[512 + c];
            const float qq = scr[256 + c] + scr[768 + c];
            part[(size_t)(by * 2) * N + bcol + c] = ss;
            part[(size_t)(by * 2 + 1) * N + bcol + c] = qq;
        }
    }
}

// ---------------------------------------------------------------------------
// BN stats final reduce: combine per-block-row partials -> scale/shift
// ---------------------------------------------------------------------------
__global__ __launch_bounds__(256) void bnstats2_kernel(const float* __restrict__ part,
                                                       const float* __restrict__ g,
                                                       const float* __restrict__ bt,
                                                       float* __restrict__ scale,
                                                       float* __restrict__ shift,
                                                       int N, int nchunk, float invM) {
    const int tx = threadIdx.x & 63;
    const int ty = threadIdx.x >> 6;
    const int c = blockIdx.x * 64 + tx;
    float s = 0.f, q = 0.f;
    for (int k = ty; k < nchunk; k += 4) {
        s += part[(size_t)(k * 2) * N + c];
        q += part[(size_t)(k * 2 + 1) * N + c];
    }
    __shared__ float sm[2][4][64];
    sm[0][ty][tx] = s;
    sm[1][ty][tx] = q;
    __syncthreads();
    if (ty == 0) {
        s = sm[0][0][tx] + sm[0][1][tx] + sm[0][2][tx] + sm[0][3][tx];
        q = sm[1][0][tx] + sm[1][1][tx] + sm[1][2][tx] + sm[1][3][tx];
        const float m = s * invM;
        const float v = fmaf(q, invM, -m * m);
        const float sc = g[c] * rsqrtf(v + EPS_BN);
        scale[c] = sc;
        shift[c] = fmaf(-m, sc, bt[c]);
    }
}

// ---------------------------------------------------------------------------
// Sparsemax (Michelot fixed-point), one wave per row, pure shfl_xor
// ---------------------------------------------------------------------------
__global__ __launch_bounds__(256) void sparsemax_kernel(const unsigned short* __restrict__ hpre,
                                                        const float* __restrict__ prior,
                                                        const float* __restrict__ x,
                                                        const float* __restrict__ scale,
                                                        const float* __restrict__ shift,
                                                        float* __restrict__ mask_o,
                                                        float* __restrict__ newp_o,
                                                        unsigned short* __restrict__ mx_bf) {
    const int lane = threadIdx.x & 63;
    const int row  = blockIdx.x * 4 + (threadIdx.x >> 6);
    const size_t base = (size_t)row * 1024;

    float z[16], p[16];
    float s0 = 0.f;
    #pragma unroll
    for (int j = 0; j < 4; ++j) {
        const int col = j * 256 + lane * 4;
        const float4 pr = *(const float4*)(prior + base + col);
        const ushort4 hp = *(const ushort4*)(hpre + base + col);
        const float4 sc = *(const float4*)(scale + col);
        const float4 sh = *(const float4*)(shift + col);
        p[j * 4 + 0] = pr.x; p[j * 4 + 1] = pr.y; p[j * 4 + 2] = pr.z; p[j * 4 + 3] = pr.w;
        z[j * 4 + 0] = pr.x * fmaf(h2f(hp.x), sc.x, sh.x);
        z[j * 4 + 1] = pr.y * fmaf(h2f(hp.y), sc.y, sh.y);
        z[j * 4 + 2] = pr.z * fmaf(h2f(hp.z), sc.z, sh.z);
        z[j * 4 + 3] = pr.w * fmaf(h2f(hp.w), sc.w, sh.w);
        s0 += z[j * 4 + 0] + z[j * 4 + 1] + z[j * 4 + 2] + z[j * 4 + 3];
    }
    #pragma unroll
    for (int off = 1; off < 64; off <<= 1) s0 += __shfl_xor(s0, off);
    float tau = (s0 - 1.0f) * (1.0f / 1024.0f);

    for (int it = 0; it < 32; ++it) {
        float s = 0.f, c = 0.f;
        #pragma unroll
        for (int j = 0; j < 16; ++j)
            if (z[j] > tau) { s += z[j]; c += 1.f; }
        #pragma unroll
        for (int off = 1; off < 64; off <<= 1) {
            s += __shfl_xor(s, off);
            c += __shfl_xor(c, off);
        }
        const float nt = (s - 1.0f) / c;
        if (nt == tau) break;   // wave-uniform
        tau = nt;
    }

    #pragma unroll
    for (int j = 0; j < 4; ++j) {
        const int col = j * 256 + lane * 4;
        const float4 xv = *(const float4*)(x + base + col);
        float m[4];
        #pragma unroll
        for (int k = 0; k < 4; ++k) m[k] = fmaxf(z[j * 4 + k] - tau, 0.f);
        *(float4*)(mask_o + base + col) = make_float4(m[0], m[1], m[2], m[3]);
        *(float4*)(newp_o + base + col) = make_float4(
            p[j * 4 + 0] * (GAMMA_C - m[0]), p[j * 4 + 1] * (GAMMA_C - m[1]),
            p[j * 4 + 2] * (GAMMA_C - m[2]), p[j * 4 + 3] * (GAMMA_C - m[3]));
        ushort4 q;
        q.x = f2b(m[0] * xv.x); q.y = f2b(m[1] * xv.y);
        q.z = f2b(m[2] * xv.z); q.w = f2b(m[3] * xv.w);
        *(ushort4*)(mx_bf + base + col) = q;
    }
}

// ---------------------------------------------------------------------------
// GLU (layers 1-3): value fp16 (uv), gate bf16 (ug), residual bf16 in-place.
// 8 elems/thread -> 16B loads/stores (G13 sweet spot). Add in f32 regs.
// ---------------------------------------------------------------------------
__global__ __launch_bounds__(256) void glu_kernel(const unsigned short* __restrict__ uv,
                                                  const unsigned short* __restrict__ ug,
                                                  const float* __restrict__ scale,
                                                  const float* __restrict__ shift,
                                                  unsigned short* __restrict__ h,
                                                  int residual) {
    const int i = blockIdx.x * 256 + threadIdx.x;   // over B*H/8
    const int r = i >> 7;
    const int c = (i & 127) * 8;
    const size_t ob = (size_t)r * 1024 + c;
    const u16x8 ua = *(const u16x8*)(uv + ob);
    const u16x8 ug8 = *(const u16x8*)(ug + ob);

    float o[8];
    #pragma unroll
    for (int j = 0; j < 8; ++j) {
        const float sa = scale[c + j];
        const float sha = shift[c + j];
        const float sb = scale[1024 + c + j];
        const float shb = shift[1024 + c + j];
        const float va = fmaf(h2f(ua[j]), sa, sha);
        const float vb = fmaf(b2f(ug8[j]), sb, shb);
        o[j] = va / (1.f + __expf(-vb));
    }
    if (residual) {
        const u16x8 hv = *(const u16x8*)(h + ob);
        #pragma unroll
        for (int j = 0; j < 8; ++j)
            o[j] = (o[j] + b2f(hv[j])) * SQRT_HALF_C;
    }
    u16x8 q;
    #pragma unroll
    for (int j = 0; j < 8; ++j) q[j] = f2b(o[j]);
    *(u16x8*)(h + ob) = q;
}

// ---------------------------------------------------------------------------
// GLU (layer 4) + split: a_out (f32), relu(d) (f32) + bf16 into SEPARATE buf
// 8 elems/thread; branch at c<512 is thread-uniform (c multiple of 8)
// ---------------------------------------------------------------------------
__global__ __launch_bounds__(256) void glu_final_kernel(const unsigned short* __restrict__ uv,
                                                        const unsigned short* __restrict__ ug,
                                                        const float* __restrict__ scale,
                                                        const float* __restrict__ shift,
                                                        const unsigned short* __restrict__ hprev,
                                                        float* __restrict__ aout,
                                                        float* __restrict__ outp,
                                                        unsigned short* __restrict__ outb) {
    const int i = blockIdx.x * 256 + threadIdx.x;   // over B*H/8
    const int r = i >> 7;
    const int c = (i & 127) * 8;
    const size_t ob0 = (size_t)r * 1024 + c;
    const u16x8 ua = *(const u16x8*)(uv + ob0);
    const u16x8 ug8 = *(const u16x8*)(ug + ob0);
    const u16x8 hv = *(const u16x8*)(hprev + ob0);

    float o[8];
    #pragma unroll
    for (int j = 0; j < 8; ++j) {
        const float sa = scale[c + j];
        const float sha = shift[c + j];
        const float sb = scale[1024 + c + j];
        const float shb = shift[1024 + c + j];
        const float va = fmaf(h2f(ua[j]), sa, sha);
        const float vb = fmaf(b2f(ug8[j]), sb, shb);
        o[j] = (va / (1.f + __expf(-vb)) + b2f(hv[j])) * SQRT_HALF_C;
    }

    if (c < 512) {
        #pragma unroll
        for (int j = 0; j < 8; ++j) o[j] = fmaxf(o[j], 0.f);
        const size_t ob = (size_t)r * 512 + c;
        *(float4*)(outp + ob)     = make_float4(o[0], o[1], o[2], o[3]);
        *(float4*)(outp + ob + 4) = make_float4(o[4], o[5], o[6], o[7]);
        u16x8 q;
        #pragma unroll
        for (int j = 0; j < 8; ++j) q[j] = f2b(o[j]);
        *(u16x8*)(outb + ob) = q;
    } else {
        const size_t ob = (size_t)r * 512 + (c - 512);
        *(float4*)(aout + ob)     = make_float4(o[0], o[1], o[2], o[3]);
        *(float4*)(aout + ob + 4) = make_float4(o[4], o[5], o[6], o[7]);
    }
}

// ---------------------------------------------------------------------------
extern "C" void kernel_launch(void* const* d_in, const int* in_sizes, int n_in,
                              void* d_out, int out_size, void* d_ws, size_t ws_size,
                              hipStream_t stream) {
    const float* a      = (const float*)d_in[0];
    const float* x      = (const float*)d_in[1];
    const float* prior  = (const float*)d_in[2];
    const float* W_att  = (const float*)d_in[3];
    const float* b_att  = (const float*)d_in[4];
    const float* g_att  = (const float*)d_in[5];
    const float* bt_att = (const float*)d_in[6];
    const float* Wl[4]  = {(const float*)d_in[7],  (const float*)d_in[11],
                           (const float*)d_in[15], (const float*)d_in[19]};
    const float* bl[4]  = {(const float*)d_in[8],  (const float*)d_in[12],
                           (const float*)d_in[16], (const float*)d_in[20]};
    const float* gl[4]  = {(const float*)d_in[9],  (const float*)d_in[13],
                           (const float*)d_in[17], (const float*)d_in[21]};
    const float* btl[4] = {(const float*)d_in[10], (const float*)d_in[14],
                           (const float*)d_in[18], (const float*)d_in[22]};
    const float* W_agg  = (const float*)d_in[23];
    const float* b_agg  = (const float*)d_in[24];

    constexpr int B = 16384, D = 1024, Na = 512, Nd = 512, H = 1024, H2 = 2048;

    char* wsp = (char*)d_ws;
    auto wsalloc = [&](size_t bytes) {
        void* p = (void*)wsp;
        wsp += (bytes + 255) & ~(size_t)255;
        return p;
    };
    unsigned short* u_hf  = (unsigned short*)wsalloc((size_t)B * H * 2);  // fp16 value half (also hpre)
    unsigned short* u_gbf = (unsigned short*)wsalloc((size_t)B * H * 2);  // gate half (bf16)
    unsigned short* io_bf = (unsigned short*)wsalloc((size_t)B * H * 2);  // masked_x / h (bf16, in-place chain)
    unsigned short* a_bf  = (unsigned short*)wsalloc((size_t)B * Na * 2); // bf16 a, later relu(d)
    unsigned short* wt_att = (unsigned short*)wsalloc((size_t)D * Na * 2);
    unsigned short* wtl    = (unsigned short*)wsalloc((size_t)4 * H2 * D * 2);
    unsigned short* wt_agg = (unsigned short*)wsalloc((size_t)D * Nd * 2);
    float* part   = (float*)wsalloc((size_t)128 * 2 * 2048 * 4);
    float* sscale = (float*)wsalloc(2048 * 4);
    float* sshift = (float*)wsalloc(2048 * 4);

    float* out = (float*)d_out;
    float* aout_o = out;
    float* outp_o = out + (size_t)B * Nd;
    float* mask_o = outp_o + (size_t)B * Na;
    float* agg_o  = mask_o + (size_t)B * D;
    float* newp_o = agg_o + (size_t)B * D;

    // 1. input / weight conversion (single merged launch)
    convert_all_kernel<<<10496, 256, 0, stream>>>(a, a_bf, W_att, wt_att,
                                                  Wl[0], Wl[1], Wl[2], Wl[3], wtl,
                                                  W_agg, wt_agg);

    // 2. attention GEMM (+fused stats, fp16 out) + BN reduce + sparsemax
    gemm256_kernel<1><<<dim3(D / 256, B / 256), 512, 0, stream>>>(a_bf, wt_att, b_att,
                                                                  u_hf, nullptr, D, part, B, D, Na);
    bnstats2_kernel<<<dim3(D / 64), 256, 0, stream>>>(part, g_att, bt_att, sscale, sshift, D, B / 256, 1.0f / B);
    sparsemax_kernel<<<B / 4, 256, 0, stream>>>(u_hf, prior, x, sscale, sshift, mask_o, newp_o, io_bf);

    // 3. four GLU blocks (value half fp16, gate half bf16, bf16 residual chain)
    for (int l = 0; l < 4; ++l) {
        gemm256_kernel<1><<<dim3(H2 / 256, B / 256), 512, 0, stream>>>(io_bf, wtl + (size_t)l * H2 * D, bl[l],
                                                                       u_hf, u_gbf, H, part, B, H2, H);
        bnstats2_kernel<<<dim3(H2 / 64), 256, 0, stream>>>(part, gl[l], btl[l], sscale, sshift, H2, B / 256, 1.0f / B);
        if (l < 3)
            glu_kernel<<<(B * H / 8) / 256, 256, 0, stream>>>(u_hf, u_gbf, sscale, sshift, io_bf, l > 0);
        else
            glu_final_kernel<<<(B * H / 8) / 256, 256, 0, stream>>>(u_hf, u_gbf, sscale, sshift, io_bf,
                                                                    aout_o, outp_o, a_bf);
    }

    // 4. aggregate GEMM (f32 out, no stats)
    gemm256_kernel<0><<<dim3(D / 256, B / 256), 512, 0, stream>>>(a_bf, wt_agg, b_agg,
                                                                  agg_o, nullptr, D, nullptr, B, D, Nd);
}